// Round 9
// baseline (65.492 us; speedup 1.0000x reference)
//
#include <hip/hip_runtime.h>

// Bilateral filter, hardcoded to reference setup:
//   x: (4, 8, 720, 1280) f32, params: (10,) f32, K=5, dilation=1, dynamic_size=3
#define BATCH 4
#define CH    8
#define HH    720
#define WW    1280
#define TW    32   // outputs per block, x
#define TH    16   // outputs per block, y (2 per thread, vertical pair)
#define SW    (TW + 4)   // 36 staged cols
#define SH    (TH + 4)   // 20 staged rows
#define DSZ   3

typedef __attribute__((ext_vector_type(2))) float    v2f;
typedef __attribute__((ext_vector_type(2))) _Float16 h2;
typedef __attribute__((ext_vector_type(4))) _Float16 h4;
typedef __attribute__((ext_vector_type(8))) _Float16 h8;

#define LOG2E      1.4426950408889634f
#define SQRT_LOG2E 1.2011224087864498f
#define SENT_H     ((_Float16)256.0f)   // (256-c)^2 >> 128 -> w = exp2(-arg) = 0 exactly

__device__ __forceinline__ float fast_exp2(float x) {
#if __has_builtin(__builtin_amdgcn_exp2f)
    return __builtin_amdgcn_exp2f(x);
#else
    return __expf(x * 0.6931471805599453f);
#endif
}

// v_dot2_f32_f16: d = a.x*b.x + a.y*b.y + c   (f32 accumulate)
__device__ __forceinline__ float fdot2(h2 a, h2 b, float c) {
#if __has_builtin(__builtin_amdgcn_fdot2)
    return __builtin_amdgcn_fdot2(a, b, c, false);
#else
    return fmaf((float)a.y, (float)b.y, fmaf((float)a.x, (float)b.x, c));
#endif
}

// v_cvt_pkrtz_f16_f32; builtin returns __fp16 vec2 -> bit-cast to our h2
__device__ __forceinline__ h2 pkrtz(float a, float b) {
    return __builtin_bit_cast(h2, __builtin_amdgcn_cvt_pkrtz(a, b));
}

// one f16 tap for one pixel; sa = ch0..3, sb = ch4..7, c[4] = center h2 pairs
__device__ __forceinline__ void tap_px(h4 sa, h4 sb, const h2 c[4], float Kj,
                                       float& n0, float& n1, float& n2, float& den)
{
    const h2 s01 = {sa.x, sa.y}, s23 = {sa.z, sa.w};
    const h2 s45 = {sb.x, sb.y}, s67 = {sb.z, sb.w};
    const h2 d01 = s01 - c[0];        // v_pk_add_f16 (neg mod)
    const h2 d23 = s23 - c[1];
    const h2 d45 = s45 - c[2];
    const h2 d67 = s67 - c[3];
    // center tap: d == 0 and Kj == 0 -> arg = 0 -> w = 1 exactly
    const float arg = fdot2(d67, d67,
                      fdot2(d45, d45,
                      fdot2(d23, d23,
                      fdot2(d01, d01, Kj))));
    const float w = fast_exp2(-arg);
    n0 = fmaf(w, (float)sa.x, n0);    // v_fma_mix candidates
    n1 = fmaf(w, (float)sa.y, n1);
    n2 = fmaf(w, (float)sa.z, n2);
    den += w;
}

// R3: never force waves/EU (spills). R4: row loop rolled. R5: 8B-stride LDS
// reads only (16B stride = 8-way conflict). R6: 2px/thread in f32 hit the
// VGPR-64 cliff; retried here in f16 where the live set is half.
__global__ __launch_bounds__(256)
void bilat_kernel(const float* __restrict__ x,
                  const float* __restrict__ params,
                  float* __restrict__ out)
{
    // packed f16, pre-scaled by |p_c|*sqrt(log2e); ch0-3 / ch4-7 split so each
    // tap is 2 x ds_read_b64 at 8B lane stride. 2*20*36*8B = 11520 B
    __shared__ __align__(16) h4 ldsA[SH][SW];
    __shared__ __align__(16) h4 ldsB[SH][SW];

    const int tid = threadIdx.x;
    const int x0 = blockIdx.x * TW;
    const int y0 = blockIdx.y * TH;
    const int b  = blockIdx.z;

    float sc[CH];
#pragma unroll
    for (int c = 0; c < CH; ++c) sc[c] = fabsf(params[c]) * SQRT_LOG2E;
    const float p8 = params[CH], p9 = params[CH + 1];
    const float sxn = p8 * p8 * LOG2E;
    const float syn = p9 * p9 * LOG2E;

    const bool interior = (blockIdx.x >= 1) && (blockIdx.x <= WW / TW - 2) &&
                          (blockIdx.y >= 1) && (blockIdx.y <= HH / TH - 2);

    if (interior) {
        // one slot = 2 adjacent pixels, all 8 channels; two 16B ds_writes.
        for (int k = tid; k < SH * (SW / 2); k += 256) {     // 360 slots
            const int r   = k / (SW / 2);
            const int duo = k - r * (SW / 2);
            const int gy  = y0 - 2 + r;
            const int gxs = x0 - 2 + 2 * duo;                // even -> 8B aligned
            const float* p0 = x + (((size_t)b * CH * HH + gy) * WW + gxs);
            v2f ch[CH];
#pragma unroll
            for (int c = 0; c < CH; ++c)
                ch[c] = *(const v2f*)(p0 + (size_t)c * HH * WW) * sc[c];
            h2 a01_0 = pkrtz(ch[0].x, ch[1].x), a23_0 = pkrtz(ch[2].x, ch[3].x);
            h2 a01_1 = pkrtz(ch[0].y, ch[1].y), a23_1 = pkrtz(ch[2].y, ch[3].y);
            h2 b45_0 = pkrtz(ch[4].x, ch[5].x), b67_0 = pkrtz(ch[6].x, ch[7].x);
            h2 b45_1 = pkrtz(ch[4].y, ch[5].y), b67_1 = pkrtz(ch[6].y, ch[7].y);
            h8 vA = {a01_0.x, a01_0.y, a23_0.x, a23_0.y,
                     a01_1.x, a01_1.y, a23_1.x, a23_1.y};
            h8 vB = {b45_0.x, b45_0.y, b67_0.x, b67_0.y,
                     b45_1.x, b45_1.y, b67_1.x, b67_1.y};
            *(h8*)&ldsA[r][2 * duo] = vA;
            *(h8*)&ldsB[r][2 * duo] = vB;
        }
    } else {
        // edge path: OOB pixel -> all channels sentinel (w underflows to 0)
        for (int k = tid; k < SH * SW; k += 256) {           // 720 slots, 3 iters
            const int r   = k / SW;
            const int col = k - r * SW;
            const int gy  = y0 - 2 + r;
            const int gx  = x0 - 2 + col;
            h4 A = {SENT_H, SENT_H, SENT_H, SENT_H};
            h4 B = A;
            if (((unsigned)gy < (unsigned)HH) & ((unsigned)gx < (unsigned)WW)) {
                const float* p0 = x + (((size_t)b * CH * HH + gy) * WW + gx);
                const size_t pl = (size_t)HH * WW;
                h2 a01 = pkrtz(p0[0] * sc[0],      p0[pl] * sc[1]);
                h2 a23 = pkrtz(p0[2 * pl] * sc[2], p0[3 * pl] * sc[3]);
                h2 b45 = pkrtz(p0[4 * pl] * sc[4], p0[5 * pl] * sc[5]);
                h2 b67 = pkrtz(p0[6 * pl] * sc[6], p0[7 * pl] * sc[7]);
                A = (h4){a01.x, a01.y, a23.x, a23.y};
                B = (h4){b45.x, b45.y, b67.x, b67.y};
            }
            ldsA[r][col] = A;
            ldsB[r][col] = B;
        }
    }
    __syncthreads();

    const int tx  = tid & 31;    // 0..31 : column
    const int ty  = tid >> 5;    // 0..7  : vertical pixel pair
    const int r0s = 2 * ty;      // staged rows touched: r0s .. r0s+5

    const h4 caA = ldsA[r0s + 2][tx + 2], cbA = ldsB[r0s + 2][tx + 2];
    const h4 caB = ldsA[r0s + 3][tx + 2], cbB = ldsB[r0s + 3][tx + 2];
    const h2 cA[4] = {{caA.x, caA.y}, {caA.z, caA.w}, {cbA.x, cbA.y}, {cbA.z, cbA.w}};
    const h2 cB[4] = {{caB.x, caB.y}, {caB.z, caB.w}, {cbB.x, cbB.y}, {cbB.z, cbB.w}};

    float n0A = 0.f, n1A = 0.f, n2A = 0.f, denA = 0.f;
    float n0B = 0.f, n1B = 0.f, n2B = 0.f, denB = 0.f;
    const float syn4 = 4.0f * syn;

    // row 0: A only (dyA = -2)
    {
        const h4* rA = &ldsA[r0s][tx];
        const h4* rB = &ldsB[r0s][tx];
        const float K1 = syn4 + sxn, K4 = fmaf(4.0f, sxn, syn4);
        const float Kj[5] = {K4, K1, syn4, K1, K4};
#pragma unroll
        for (int j = 0; j < 5; ++j)
            tap_px(rA[j], rB[j], cA, Kj[j], n0A, n1A, n2A, denA);
    }
    // rows 1..4: both pixels; rolled so one row's taps are live at a time
#pragma unroll 1
    for (int i = 1; i <= 4; ++i) {
        const float dyA = (float)(i - 2), dyB = (float)(i - 3);
        const float taprA = syn * dyA * dyA;
        const float taprB = syn * dyB * dyB;
        const float KA[5] = {fmaf(4.f, sxn, taprA), taprA + sxn, taprA,
                             taprA + sxn, fmaf(4.f, sxn, taprA)};
        const float KB[5] = {fmaf(4.f, sxn, taprB), taprB + sxn, taprB,
                             taprB + sxn, fmaf(4.f, sxn, taprB)};
        const h4* rA = &ldsA[r0s + i][tx];
        const h4* rB = &ldsB[r0s + i][tx];
#pragma unroll
        for (int j = 0; j < 5; ++j) {
            const h4 sa = rA[j];             // shared by both pixels
            const h4 sb = rB[j];
            tap_px(sa, sb, cA, KA[j], n0A, n1A, n2A, denA);
            tap_px(sa, sb, cB, KB[j], n0B, n1B, n2B, denB);
        }
    }
    // row 5: B only (dyB = +2)
    {
        const h4* rA = &ldsA[r0s + 5][tx];
        const h4* rB = &ldsB[r0s + 5][tx];
        const float K1 = syn4 + sxn, K4 = fmaf(4.0f, sxn, syn4);
        const float Kj[5] = {K4, K1, syn4, K1, K4};
#pragma unroll
        for (int j = 0; j < 5; ++j)
            tap_px(rA[j], rB[j], cB, Kj[j], n0B, n1B, n2B, denB);
    }

    const float ivA = __builtin_amdgcn_rcpf(denA);   // den >= 1 (center tap w=1)
    const float ivB = __builtin_amdgcn_rcpf(denB);
    const float u0 = __builtin_amdgcn_rcpf(fabsf(params[0]) * SQRT_LOG2E);
    const float u1 = __builtin_amdgcn_rcpf(fabsf(params[1]) * SQRT_LOG2E);
    const float u2 = __builtin_amdgcn_rcpf(fabsf(params[2]) * SQRT_LOG2E);

    const size_t plane = (size_t)HH * WW;
    const int gx = x0 + tx;
    const int gy = y0 + 2 * ty;
    const size_t base = (size_t)b * DSZ * plane + (size_t)gy * WW + gx;
    out[base]                  = n0A * ivA * u0;
    out[base + WW]             = n0B * ivB * u0;
    out[base + plane]          = n1A * ivA * u1;
    out[base + plane + WW]     = n1B * ivB * u1;
    out[base + 2 * plane]      = n2A * ivA * u2;
    out[base + 2 * plane + WW] = n2B * ivB * u2;
}

extern "C" void kernel_launch(void* const* d_in, const int* in_sizes, int n_in,
                              void* d_out, int out_size, void* d_ws, size_t ws_size,
                              hipStream_t stream)
{
    const float* x      = (const float*)d_in[0];
    const float* params = (const float*)d_in[1];
    float* out          = (float*)d_out;

    dim3 grid(WW / TW, HH / TH, BATCH);   // 40 x 45 x 4
    bilat_kernel<<<grid, 256, 0, stream>>>(x, params, out);
}

// Round 10
// 65.422 us; speedup vs baseline: 1.0011x; 1.0011x over previous
//
#include <hip/hip_runtime.h>

// Bilateral filter, hardcoded to reference setup:
//   x: (4, 8, 720, 1280) f32, params: (10,) f32, K=5, dilation=1, dynamic_size=3
#define BATCH 4
#define CH    8
#define HH    720
#define WW    1280
#define TW    32   // outputs per block, x
#define TH    8    // outputs per block, y (1 px/thread — R8 proven shell)
#define SW    (TW + 4)   // 36 staged cols
#define SH    (TH + 4)   // 12 staged rows
#define DSZ   3

typedef __attribute__((ext_vector_type(2))) float    v2f;
typedef __attribute__((ext_vector_type(2))) _Float16 h2;
typedef __attribute__((ext_vector_type(4))) _Float16 h4;
typedef __attribute__((ext_vector_type(8))) _Float16 h8;

#define LOG2E      1.4426950408889634f
#define SQRT_LOG2E 1.2011224087864498f
#define SENT_H     ((_Float16)256.0f)   // (256-c)^2*ch >> 128 -> w = exp2(-arg) = 0

__device__ __forceinline__ float fast_exp2(float x) {
#if __has_builtin(__builtin_amdgcn_exp2f)
    return __builtin_amdgcn_exp2f(x);
#else
    return __expf(x * 0.6931471805599453f);
#endif
}

// v_dot2_f32_f16: d = a.x*b.x + a.y*b.y + c   (f32 accumulate)
__device__ __forceinline__ float fdot2(h2 a, h2 b, float c) {
#if __has_builtin(__builtin_amdgcn_fdot2)
    return __builtin_amdgcn_fdot2(a, b, c, false);
#else
    return fmaf((float)a.y, (float)b.y, fmaf((float)a.x, (float)b.x, c));
#endif
}

// v_cvt_pkrtz_f16_f32; builtin returns __fp16 vec2 -> bit-cast to our h2
__device__ __forceinline__ h2 pkrtz(float a, float b) {
    return __builtin_bit_cast(h2, __builtin_amdgcn_cvt_pkrtz(a, b));
}

// one f16 tap; sa = ch0..3, sb = ch4..7, c[4] = center h2 pairs
__device__ __forceinline__ void tap_px(h4 sa, h4 sb, const h2 c[4], float Kj,
                                       float& n0, float& n1, float& n2, float& den)
{
    const h2 s01 = {sa.x, sa.y}, s23 = {sa.z, sa.w};
    const h2 s45 = {sb.x, sb.y}, s67 = {sb.z, sb.w};
    const h2 d01 = s01 - c[0];        // v_pk_add_f16 (neg mod)
    const h2 d23 = s23 - c[1];
    const h2 d45 = s45 - c[2];
    const h2 d67 = s67 - c[3];
    // center tap: d == 0 and Kj == 0 -> arg = 0 -> w = 1 exactly
    const float arg = fdot2(d67, d67,
                      fdot2(d45, d45,
                      fdot2(d23, d23,
                      fdot2(d01, d01, Kj))));
    const float w = fast_exp2(-arg);
    n0 = fmaf(w, (float)sa.x, n0);    // v_fma_mix
    n1 = fmaf(w, (float)sa.y, n1);
    n2 = fmaf(w, (float)sa.z, n2);
    den += w;
}

// compute all 5 taps of one row held in registers
__device__ __forceinline__ void row5(const h4 ra[5], const h4 rb[5], const h2 c[4],
                                     float tapr, float sxn,
                                     float& n0, float& n1, float& n2, float& den)
{
    const float K1 = tapr + sxn;
    const float K4 = fmaf(4.0f, sxn, tapr);
    const float Kj[5] = {K4, K1, tapr, K1, K4};
#pragma unroll
    for (int j = 0; j < 5; ++j)
        tap_px(ra[j], rb[j], c, Kj[j], n0, n1, n2, den);
}

// R3: never force waves/EU (spills). R5: 8B-stride LDS reads only (16B stride
// = 8-way conflict). R6/R9: 2px/thread doesn't pay. R10: rolled row loop is
// kept, but rows are REGISTER DOUBLE-BUFFERED so each row's 10 ds_read_b64
// issue one full row-compute (~130cyc) before first use (covers ~120cyc LDS
// latency per-wave) — attacks the 35% VALU-idle seen at R8.
__global__ __launch_bounds__(256)
void bilat_kernel(const float* __restrict__ x,
                  const float* __restrict__ params,
                  float* __restrict__ out)
{
    // packed f16, pre-scaled by |p_c|*sqrt(log2e); ch0-3 / ch4-7 split so each
    // tap is 2 x ds_read_b64 at 8B lane stride. 2*12*36*8B = 6912 B
    __shared__ __align__(16) h4 ldsA[SH][SW];
    __shared__ __align__(16) h4 ldsB[SH][SW];

    const int tid = threadIdx.x;
    const int x0 = blockIdx.x * TW;
    const int y0 = blockIdx.y * TH;
    const int b  = blockIdx.z;

    float sc[CH];
#pragma unroll
    for (int c = 0; c < CH; ++c) sc[c] = fabsf(params[c]) * SQRT_LOG2E;
    const float p8 = params[CH], p9 = params[CH + 1];
    const float sxn = p8 * p8 * LOG2E;
    const float syn = p9 * p9 * LOG2E;

    const bool interior = (blockIdx.x >= 1) && (blockIdx.x <= WW / TW - 2) &&
                          (blockIdx.y >= 1) && (blockIdx.y <= HH / TH - 2);

    if (interior) {
        // fast path: one slot = 2 adjacent pixels; two 16B ds_writes.
        if (tid < SH * (SW / 2)) {                       // 216 slots
            const int r   = tid / (SW / 2);
            const int duo = tid - r * (SW / 2);
            const int gy  = y0 - 2 + r;
            const int gxs = x0 - 2 + 2 * duo;            // even -> 8B aligned
            const float* p0 = x + (((size_t)b * CH * HH + gy) * WW + gxs);
            v2f ch[CH];
#pragma unroll
            for (int c = 0; c < CH; ++c)
                ch[c] = *(const v2f*)(p0 + (size_t)c * HH * WW) * sc[c];
            h2 a01_0 = pkrtz(ch[0].x, ch[1].x), a23_0 = pkrtz(ch[2].x, ch[3].x);
            h2 a01_1 = pkrtz(ch[0].y, ch[1].y), a23_1 = pkrtz(ch[2].y, ch[3].y);
            h2 b45_0 = pkrtz(ch[4].x, ch[5].x), b67_0 = pkrtz(ch[6].x, ch[7].x);
            h2 b45_1 = pkrtz(ch[4].y, ch[5].y), b67_1 = pkrtz(ch[6].y, ch[7].y);
            h8 vA = {a01_0.x, a01_0.y, a23_0.x, a23_0.y,
                     a01_1.x, a01_1.y, a23_1.x, a23_1.y};
            h8 vB = {b45_0.x, b45_0.y, b67_0.x, b67_0.y,
                     b45_1.x, b45_1.y, b67_1.x, b67_1.y};
            *(h8*)&ldsA[r][2 * duo] = vA;
            *(h8*)&ldsB[r][2 * duo] = vB;
        }
    } else {
        // edge path: OOB pixel -> all channels sentinel (w underflows to 0)
        for (int k = tid; k < SH * SW; k += 256) {       // 432 slots, 2 iters
            const int r   = k / SW;
            const int col = k - r * SW;
            const int gy  = y0 - 2 + r;
            const int gx  = x0 - 2 + col;
            h4 A = {SENT_H, SENT_H, SENT_H, SENT_H};
            h4 B = A;
            if (((unsigned)gy < (unsigned)HH) & ((unsigned)gx < (unsigned)WW)) {
                const float* p0 = x + (((size_t)b * CH * HH + gy) * WW + gx);
                const size_t pl = (size_t)HH * WW;
                h2 a01 = pkrtz(p0[0] * sc[0],      p0[pl] * sc[1]);
                h2 a23 = pkrtz(p0[2 * pl] * sc[2], p0[3 * pl] * sc[3]);
                h2 b45 = pkrtz(p0[4 * pl] * sc[4], p0[5 * pl] * sc[5]);
                h2 b67 = pkrtz(p0[6 * pl] * sc[6], p0[7 * pl] * sc[7]);
                A = (h4){a01.x, a01.y, a23.x, a23.y};
                B = (h4){b45.x, b45.y, b67.x, b67.y};
            }
            ldsA[r][col] = A;
            ldsB[r][col] = B;
        }
    }
    __syncthreads();

    const int lx = tid & 31;
    const int ly = tid >> 5;

    const h4 ca = ldsA[ly + 2][lx + 2];
    const h4 cb = ldsB[ly + 2][lx + 2];
    const h2 c[4] = {{ca.x, ca.y}, {ca.z, ca.w}, {cb.x, cb.y}, {cb.z, cb.w}};

    float n0 = 0.f, n1 = 0.f, n2 = 0.f, den = 0.f;

    // --- register double-buffered row pipeline ---
    h4 A0[5], B0[5], A1[5], B1[5];
#pragma unroll
    for (int j = 0; j < 5; ++j) { A0[j] = ldsA[ly][lx + j];     B0[j] = ldsB[ly][lx + j]; }
#pragma unroll
    for (int j = 0; j < 5; ++j) { A1[j] = ldsA[ly + 1][lx + j]; B1[j] = ldsB[ly + 1][lx + j]; }

    // row 0 (dy = -2); rows 1/2 loads already in flight / issued next
    row5(A0, B0, c, 4.0f * syn, sxn, n0, n1, n2, den);

#pragma unroll 1
    for (int it = 0; it < 2; ++it) {
        const int r2 = 2 * it + 2;                 // row going into buffer 0
        // issue row r2 loads (buffer 0 was just consumed)
#pragma unroll
        for (int j = 0; j < 5; ++j) { A0[j] = ldsA[ly + r2][lx + j]; B0[j] = ldsB[ly + r2][lx + j]; }
        // compute row 2it+1 from buffer 1 (its loads issued one phase ago)
        {
            const float dyf = (float)(2 * it + 1 - 2);
            row5(A1, B1, c, syn * dyf * dyf, sxn, n0, n1, n2, den);
        }
        // issue row 2it+3 loads into buffer 1 (skip past last row)
        if (it == 0) {
#pragma unroll
            for (int j = 0; j < 5; ++j) { A1[j] = ldsA[ly + 3][lx + j]; B1[j] = ldsB[ly + 3][lx + j]; }
        }
        // compute row r2 from buffer 0
        {
            const float dyf = (float)(r2 - 2);
            row5(A0, B0, c, syn * dyf * dyf, sxn, n0, n1, n2, den);
        }
    }

    const float invden = __builtin_amdgcn_rcpf(den);   // den >= 1 (center tap w=1)
    const float u0 = __builtin_amdgcn_rcpf(fabsf(params[0]) * SQRT_LOG2E);
    const float u1 = __builtin_amdgcn_rcpf(fabsf(params[1]) * SQRT_LOG2E);
    const float u2 = __builtin_amdgcn_rcpf(fabsf(params[2]) * SQRT_LOG2E);

    const size_t plane = (size_t)HH * WW;
    const int gx = x0 + lx;
    const int gy = y0 + ly;
    const size_t base = (size_t)b * DSZ * plane + (size_t)gy * WW + gx;
    out[base]             = n0 * invden * u0;
    out[base + plane]     = n1 * invden * u1;
    out[base + 2 * plane] = n2 * invden * u2;
}

extern "C" void kernel_launch(void* const* d_in, const int* in_sizes, int n_in,
                              void* d_out, int out_size, void* d_ws, size_t ws_size,
                              hipStream_t stream)
{
    const float* x      = (const float*)d_in[0];
    const float* params = (const float*)d_in[1];
    float* out          = (float*)d_out;

    dim3 grid(WW / TW, HH / TH, BATCH);   // 40 x 90 x 4
    bilat_kernel<<<grid, 256, 0, stream>>>(x, params, out);
}

// Round 11
// 61.432 us; speedup vs baseline: 1.0661x; 1.0649x over previous
//
#include <hip/hip_runtime.h>

// Bilateral filter, hardcoded to reference setup:
//   x: (4, 8, 720, 1280) f32, params: (10,) f32, K=5, dilation=1, dynamic_size=3
#define BATCH 4
#define CH    8
#define HH    720
#define WW    1280
#define TW    32   // outputs per block, x
#define TH    8    // outputs per block, y (1 px/thread — R8 proven shell)
#define SW    (TW + 4)   // 36 staged cols
#define SH    (TH + 4)   // 12 staged rows
#define DSZ   3

typedef __attribute__((ext_vector_type(2))) float    v2f;
typedef __attribute__((ext_vector_type(2))) _Float16 h2;
typedef __attribute__((ext_vector_type(4))) _Float16 h4;
typedef __attribute__((ext_vector_type(8))) _Float16 h8;

#define LOG2E      1.4426950408889634f
#define SQRT_LOG2E 1.2011224087864498f
#define SQRT2      1.4142135623730951f
#define SENT_H     ((_Float16)362.0f)   // sentinel (= 256*sqrt2 scale-equivalent)

__device__ __forceinline__ float fast_exp2(float x) {
#if __has_builtin(__builtin_amdgcn_exp2f)
    return __builtin_amdgcn_exp2f(x);
#else
    return __expf(x * 0.6931471805599453f);
#endif
}

// v_dot2_f32_f16: d = a.x*b.x + a.y*b.y + c   (f32 accumulate)
__device__ __forceinline__ float fdot2(h2 a, h2 b, float c) {
#if __has_builtin(__builtin_amdgcn_fdot2)
    return __builtin_amdgcn_fdot2(a, b, c, false);
#else
    return fmaf((float)a.y, (float)b.y, fmaf((float)a.x, (float)b.x, c));
#endif
}

// v_cvt_pkrtz_f16_f32; builtin returns __fp16 vec2 -> bit-cast to our h2
__device__ __forceinline__ h2 pkrtz(float a, float b) {
    return __builtin_bit_cast(h2, __builtin_amdgcn_cvt_pkrtz(a, b));
}

// self-dot chain: X = sum_ch v^2 (f32), SAME nesting as the tap chain so the
// center tap's arg cancels to ~0 exactly.
__device__ __forceinline__ float selfdot(h4 a, h4 b) {
    const h2 p01 = {a.x, a.y}, p23 = {a.z, a.w};
    const h2 p45 = {b.x, b.y}, p67 = {b.z, b.w};
    return fdot2(p67, p67, fdot2(p45, p45, fdot2(p23, p23, fdot2(p01, p01, 0.f))));
}

// R3: never force waves/EU (spills). R5: 8B-stride LDS reads only. R6/R9:
// 2px/thread doesn't pay. R10: batched reg double-buffering doesn't pay.
// R11: dot-form — stage sqrt2-scaled f16 channels + f32 S2=0.5*sum(s'^2);
// per tap arg = sum(s'c') - S2s - (S2c + K): kills the 4 pk_subs (VALU -23%)
// for +1 cheap stride-4 f32 LDS read per tap (fuses to ds_read2_b32).
__global__ __launch_bounds__(256)
void bilat_kernel(const float* __restrict__ x,
                  const float* __restrict__ params,
                  float* __restrict__ out)
{
    // packed f16, pre-scaled by |p_c|*sqrt(log2e)*sqrt2; ch0-3 / ch4-7 split.
    __shared__ __align__(16) h4 ldsA[SH][SW];   // 3456 B
    __shared__ __align__(16) h4 ldsB[SH][SW];   // 3456 B
    __shared__ float ldsS[SH][SW];              // 1728 B  (S2 plane)

    const int tid = threadIdx.x;
    const int x0 = blockIdx.x * TW;
    const int y0 = blockIdx.y * TH;
    const int b  = blockIdx.z;

    float sc[CH];
#pragma unroll
    for (int c = 0; c < CH; ++c) sc[c] = fabsf(params[c]) * (SQRT_LOG2E * SQRT2);
    const float p8 = params[CH], p9 = params[CH + 1];
    const float sxn = p8 * p8 * LOG2E;
    const float syn = p9 * p9 * LOG2E;

    const bool interior = (blockIdx.x >= 1) && (blockIdx.x <= WW / TW - 2) &&
                          (blockIdx.y >= 1) && (blockIdx.y <= HH / TH - 2);

    if (interior) {
        // fast path: one slot = 2 adjacent pixels; two 16B ds_writes + one 8B.
        if (tid < SH * (SW / 2)) {                       // 216 slots
            const int r   = tid / (SW / 2);
            const int duo = tid - r * (SW / 2);
            const int gy  = y0 - 2 + r;
            const int gxs = x0 - 2 + 2 * duo;            // even -> 8B aligned
            const float* p0 = x + (((size_t)b * CH * HH + gy) * WW + gxs);
            v2f ch[CH];
#pragma unroll
            for (int c = 0; c < CH; ++c)
                ch[c] = *(const v2f*)(p0 + (size_t)c * HH * WW) * sc[c];
            h2 a01_0 = pkrtz(ch[0].x, ch[1].x), a23_0 = pkrtz(ch[2].x, ch[3].x);
            h2 a01_1 = pkrtz(ch[0].y, ch[1].y), a23_1 = pkrtz(ch[2].y, ch[3].y);
            h2 b45_0 = pkrtz(ch[4].x, ch[5].x), b67_0 = pkrtz(ch[6].x, ch[7].x);
            h2 b45_1 = pkrtz(ch[4].y, ch[5].y), b67_1 = pkrtz(ch[6].y, ch[7].y);
            h8 vA = {a01_0.x, a01_0.y, a23_0.x, a23_0.y,
                     a01_1.x, a01_1.y, a23_1.x, a23_1.y};
            h8 vB = {b45_0.x, b45_0.y, b67_0.x, b67_0.y,
                     b45_1.x, b45_1.y, b67_1.x, b67_1.y};
            *(h8*)&ldsA[r][2 * duo] = vA;
            *(h8*)&ldsB[r][2 * duo] = vB;
            const h4 A0 = {a01_0.x, a01_0.y, a23_0.x, a23_0.y};
            const h4 B0 = {b45_0.x, b45_0.y, b67_0.x, b67_0.y};
            const h4 A1 = {a01_1.x, a01_1.y, a23_1.x, a23_1.y};
            const h4 B1 = {b45_1.x, b45_1.y, b67_1.x, b67_1.y};
            v2f s2 = {0.5f * selfdot(A0, B0), 0.5f * selfdot(A1, B1)};
            *(v2f*)&ldsS[r][2 * duo] = s2;
        }
    } else {
        // edge path: OOB pixel -> all channels sentinel (S2 huge -> w = 0)
        for (int k = tid; k < SH * SW; k += 256) {       // 432 slots, 2 iters
            const int r   = k / SW;
            const int col = k - r * SW;
            const int gy  = y0 - 2 + r;
            const int gx  = x0 - 2 + col;
            h4 A = {SENT_H, SENT_H, SENT_H, SENT_H};
            h4 B = A;
            if (((unsigned)gy < (unsigned)HH) & ((unsigned)gx < (unsigned)WW)) {
                const float* p0 = x + (((size_t)b * CH * HH + gy) * WW + gx);
                const size_t pl = (size_t)HH * WW;
                h2 a01 = pkrtz(p0[0] * sc[0],      p0[pl] * sc[1]);
                h2 a23 = pkrtz(p0[2 * pl] * sc[2], p0[3 * pl] * sc[3]);
                h2 b45 = pkrtz(p0[4 * pl] * sc[4], p0[5 * pl] * sc[5]);
                h2 b67 = pkrtz(p0[6 * pl] * sc[6], p0[7 * pl] * sc[7]);
                A = (h4){a01.x, a01.y, a23.x, a23.y};
                B = (h4){b45.x, b45.y, b67.x, b67.y};
            }
            ldsA[r][col] = A;
            ldsB[r][col] = B;
            ldsS[r][col] = 0.5f * selfdot(A, B);   // sentinel -> ~5.2e5
        }
    }
    __syncthreads();

    const int lx = tid & 31;
    const int ly = tid >> 5;

    const h4 ca = ldsA[ly + 2][lx + 2];
    const h4 cb = ldsB[ly + 2][lx + 2];
    const float S2c = ldsS[ly + 2][lx + 2];
    const h2 c01 = {ca.x, ca.y}, c23 = {ca.z, ca.w};
    const h2 c45 = {cb.x, cb.y}, c67 = {cb.z, cb.w};

    float n0 = 0.f, n1 = 0.f, n2 = 0.f, den = 0.f;

    // Rolled row loop: one row's 10 b64 + 5 b32 tap-values live at a time.
#pragma unroll 1
    for (int i = 0; i < 5; ++i) {
        const float dyf  = (float)(i - 2);
        const float tapr = syn * dyf * dyf;
        // KS[j] = -(K_j + S2c), K_j = tapr + sxn*dx^2
        const float ks0 = -(tapr + S2c);               // dx = 0
        const float ks1 = ks0 - sxn;                   // |dx| = 1
        const float ks4 = fmaf(-4.0f, sxn, ks0);       // |dx| = 2
        const float KS[5] = {ks4, ks1, ks0, ks1, ks4};
        const h4*    rA = &ldsA[ly + i][lx];
        const h4*    rB = &ldsB[ly + i][lx];
        const float* rS = &ldsS[ly + i][lx];

#pragma unroll
        for (int j = 0; j < 5; ++j) {
            const h4 sa = rA[j];              // ds_read_b64, 8B lane stride
            const h4 sb = rB[j];
            const float seed = KS[j] - rS[j]; // ds_read2_b32-fused, 4B stride
            const h2 s01 = {sa.x, sa.y}, s23 = {sa.z, sa.w};
            const h2 s45 = {sb.x, sb.y}, s67 = {sb.z, sb.w};
            // arg = sum(s'c') - S2s - S2c - K  (= -log2 weight, <= ~0)
            const float arg = fdot2(s67, c67,
                              fdot2(s45, c45,
                              fdot2(s23, c23,
                              fdot2(s01, c01, seed))));
            const float w = fast_exp2(arg);   // center tap: arg ~= 0 -> w ~= 1
            n0 = fmaf(w, (float)sa.x, n0);    // v_fma_mix
            n1 = fmaf(w, (float)sa.y, n1);
            n2 = fmaf(w, (float)sa.z, n2);
            den += w;
        }
    }

    const float invden = __builtin_amdgcn_rcpf(den);   // den >= ~1 (center tap)
    const float u0 = __builtin_amdgcn_rcpf(fabsf(params[0]) * (SQRT_LOG2E * SQRT2));
    const float u1 = __builtin_amdgcn_rcpf(fabsf(params[1]) * (SQRT_LOG2E * SQRT2));
    const float u2 = __builtin_amdgcn_rcpf(fabsf(params[2]) * (SQRT_LOG2E * SQRT2));

    const size_t plane = (size_t)HH * WW;
    const int gx = x0 + lx;
    const int gy = y0 + ly;
    const size_t base = (size_t)b * DSZ * plane + (size_t)gy * WW + gx;
    out[base]             = n0 * invden * u0;
    out[base + plane]     = n1 * invden * u1;
    out[base + 2 * plane] = n2 * invden * u2;
}

extern "C" void kernel_launch(void* const* d_in, const int* in_sizes, int n_in,
                              void* d_out, int out_size, void* d_ws, size_t ws_size,
                              hipStream_t stream)
{
    const float* x      = (const float*)d_in[0];
    const float* params = (const float*)d_in[1];
    float* out          = (float*)d_out;

    dim3 grid(WW / TW, HH / TH, BATCH);   // 40 x 90 x 4
    bilat_kernel<<<grid, 256, 0, stream>>>(x, params, out);
}